// Round 10
// baseline (25.274 us; speedup 1.0000x reference)
//
#include <hip/hip_runtime.h>
#include <math.h>

#define DT 0.2f
#define LEN_HIST 16
#define TPB 256

// v5 = v4 (triangle covariance, simple-form update, single dispatch, no LDS)
// + register-packed aligned float4 stores: lane group g=b&3 emits fixed
// pattern; all float4 contents are own-track or wave-uniform values.
__global__ __launch_bounds__(TPB) void kalman_v5(
    const float* __restrict__ hist,
    const float* __restrict__ vsx_p, const float* __restrict__ vsy_p,
    const float* __restrict__ asx_p, const float* __restrict__ asy_p,
    const float* __restrict__ GR_p,  const float* __restrict__ coefG_p,
    float* __restrict__ out, int B, int len_pred, int pack4)
{
    const int b = blockIdx.x * TPB + threadIdx.x;
    if (b >= B) return;

    // ---- measurements first: 16 coalesced float2 loads, all in flight ----
    float2 z[LEN_HIST];
    #pragma unroll
    for (int t = 0; t < LEN_HIST; ++t)
        z[t] = *reinterpret_cast<const float2*>(hist + ((size_t)t * B + b) * 2);

    // ---- constants: Q (triangle), R ----
    const float d = DT;
    const float Gv0 = DT * DT * 0.5f, Gv1 = DT, Gv2 = DT * DT * 0.5f, Gv3 = DT;
    const float ax2 = asx_p[0] * asx_p[0];
    const float ay2 = asy_p[0] * asy_p[0];
    const float g0 = Gv0 * tanhf(coefG_p[0]);
    const float g1 = Gv1 * tanhf(coefG_p[1]);
    const float g2 = Gv2 * tanhf(coefG_p[2]);
    const float g3 = Gv3 * tanhf(coefG_p[3]);
    const float Q00 = g0 * g0 * ax2, Q01 = g0 * g1 * ax2;
    const float Q02 = g0 * g2,       Q03 = g0 * g3;
    const float Q11 = g1 * g1 * ax2, Q12 = g1 * g2, Q13 = g1 * g3;
    const float Q22 = g2 * g2 * ay2, Q23 = g2 * g3 * ay2, Q33 = g3 * g3 * ay2;
    const float GR0 = GR_p[0], GR1 = GR_p[1];
    const float R00 = GR0 * GR0, R01 = GR0 * GR1, R11 = GR1 * GR1;

    // ---- init ----
    float X0 = z[0].x, X1 = (z[1].x - z[0].x) / DT;
    float X2 = z[0].y, X3 = (z[1].y - z[0].y) / DT;
    float P00 = R00,                 P01 = 0.f, P02 = 0.f, P03 = 0.f;
    float P11 = vsx_p[0] * vsx_p[0], P12 = 0.f, P13 = 0.f;
    float P22 = R11,                 P23 = 0.f;
    float P33 = vsy_p[0] * vsy_p[0];

    // ---- filter: 15 updates, symmetric triangle, simple-form (v4) ----
    #pragma unroll
    for (int t = 1; t < LEN_HIST; ++t) {
        const float n00 = P00 + d * (P01 + P01 + d * P11) + Q00;
        const float n01 = P01 + d * P11 + Q01;
        const float n02 = P02 + d * (P03 + P12 + d * P13) + Q02;
        const float n03 = P03 + d * P13 + Q03;
        const float n11 = P11 + Q11;
        const float n12 = P12 + d * P13 + Q12;
        const float n13 = P13 + Q13;
        const float n22 = P22 + d * (P23 + P23 + d * P33) + Q22;
        const float n23 = P23 + d * P33 + Q23;
        const float n33 = P33 + Q33;

        X0 += d * X1; X2 += d * X3;
        const float y0 = z[t].x - X0;
        const float y1 = z[t].y - X2;

        const float S00 = n00 + R00, S01 = n02 + R01, S11 = n22 + R11;
        const float inv = 1.0f / (S00 * S11 - S01 * S01);
        const float Si00 = S11 * inv, Si01 = -S01 * inv, Si11 = S00 * inv;

        const float K00 = n00 * Si00 + n02 * Si01, K01 = n00 * Si01 + n02 * Si11;
        const float K10 = n01 * Si00 + n12 * Si01, K11 = n01 * Si01 + n12 * Si11;
        const float K20 = n02 * Si00 + n22 * Si01, K21 = n02 * Si01 + n22 * Si11;
        const float K30 = n03 * Si00 + n23 * Si01, K31 = n03 * Si01 + n23 * Si11;

        X0 += K00 * y0 + K01 * y1;
        X1 += K10 * y0 + K11 * y1;
        X2 += K20 * y0 + K21 * y1;
        X3 += K30 * y0 + K31 * y1;

        P00 = n00 - K00 * n00 - K01 * n02;
        P01 = n01 - K00 * n01 - K01 * n12;
        P02 = n02 - K00 * n02 - K01 * n22;
        P03 = n03 - K00 * n03 - K01 * n23;
        P11 = n11 - K10 * n01 - K11 * n12;
        P12 = n12 - K10 * n02 - K11 * n22;
        P13 = n13 - K10 * n03 - K11 * n23;
        P22 = n22 - K20 * n02 - K21 * n22;
        P23 = n23 - K20 * n03 - K21 * n23;
        P33 = n33 - K30 * n03 - K31 * n23;
    }

    // ---- prediction ----
    if (pack4) {
        // packed float4 path: group of 4 consecutive tracks -> 5 float4s;
        // every float4 is own-track mux/muy + wave-uniform sx/sy/rho.
        const int q = b >> 2, g = b & 3;
        float4* __restrict__ out4 = reinterpret_cast<float4*>(out);
        const size_t st4 = ((size_t)B * 5) >> 2;
        float4* o1 = out4 + (size_t)q * 5 + g;
        float4* o2 = out4 + (size_t)q * 5 + 4;   // only g==3 uses

        for (int l = 0; l < len_pred; ++l) {
            const float n00 = P00 + d * (P01 + P01 + d * P11) + Q00;
            const float n01 = P01 + d * P11 + Q01;
            const float n02 = P02 + d * (P03 + P12 + d * P13) + Q02;
            const float n03 = P03 + d * P13 + Q03;
            const float n11 = P11 + Q11;
            const float n12 = P12 + d * P13 + Q12;
            const float n13 = P13 + Q13;
            const float n22 = P22 + d * (P23 + P23 + d * P33) + Q22;
            const float n23 = P23 + d * P33 + Q23;
            const float n33 = P33 + Q33;
            P00 = n00; P01 = n01; P02 = n02; P03 = n03;
            P11 = n11; P12 = n12; P13 = n13;
            P22 = n22; P23 = n23; P33 = n33;

            X0 += d * X1; X2 += d * X3;

            const float sx = sqrtf(P00);
            const float sy = sqrtf(P22);
            const float rho = P02 / (sx * sy);

            float4 v;
            v.x = (g == 0) ? X0 : (g == 1) ? rho : (g == 2) ? sy : sx;
            v.y = (g == 0) ? X2 : (g == 1) ? X0  : (g == 2) ? rho : sy;
            v.z = (g == 0) ? sx : (g == 1) ? X2  : (g == 2) ? X0  : rho;
            v.w = (g == 0) ? sy : (g == 1) ? sx  : (g == 2) ? X2  : X0;
            *o1 = v; o1 += st4;
            if (g == 3) { *o2 = make_float4(X2, sx, sy, rho); o2 += st4; }
        }
    } else {
        // scalar fallback (B % 4 != 0)
        float* o = out + (size_t)b * 5;
        const size_t ostride = (size_t)B * 5;
        for (int l = 0; l < len_pred; ++l) {
            const float n00 = P00 + d * (P01 + P01 + d * P11) + Q00;
            const float n01 = P01 + d * P11 + Q01;
            const float n02 = P02 + d * (P03 + P12 + d * P13) + Q02;
            const float n03 = P03 + d * P13 + Q03;
            const float n11 = P11 + Q11;
            const float n12 = P12 + d * P13 + Q12;
            const float n13 = P13 + Q13;
            const float n22 = P22 + d * (P23 + P23 + d * P33) + Q22;
            const float n23 = P23 + d * P33 + Q23;
            const float n33 = P33 + Q33;
            P00 = n00; P01 = n01; P02 = n02; P03 = n03;
            P11 = n11; P12 = n12; P13 = n13;
            P22 = n22; P23 = n23; P33 = n33;

            X0 += d * X1; X2 += d * X3;

            const float sx = sqrtf(P00);
            const float sy = sqrtf(P22);
            const float rho = P02 / (sx * sy);

            o[0] = X0; o[1] = X2; o[2] = sx; o[3] = sy; o[4] = rho;
            o += ostride;
        }
    }
}

extern "C" void kernel_launch(void* const* d_in, const int* in_sizes, int n_in,
                              void* d_out, int out_size, void* d_ws, size_t ws_size,
                              hipStream_t stream) {
    const float* hist  = (const float*)d_in[0];
    const float* vsx   = (const float*)d_in[1];
    const float* vsy   = (const float*)d_in[2];
    const float* asx   = (const float*)d_in[3];
    const float* asy   = (const float*)d_in[4];
    const float* GR    = (const float*)d_in[5];
    const float* coefG = (const float*)d_in[6];
    float* out = (float*)d_out;

    int B = in_sizes[0] / (LEN_HIST * 2);
    int len_pred = out_size / (B * 5);
    int pack4 = (B % 4 == 0) ? 1 : 0;

    int grid = (B + TPB - 1) / TPB;
    kalman_v5<<<grid, TPB, 0, stream>>>(hist, vsx, vsy, asx, asy, GR, coefG,
                                        out, B, len_pred, pack4);
}

// Round 11
// 24.612 us; speedup vs baseline: 1.0269x; 1.0269x over previous
//
#include <hip/hip_runtime.h>
#include <math.h>

#define DT 0.2f
#define LEN_HIST 16
#define TPB 256

// v6 = v4 (triangle covariance filter, simple-form update, single dispatch,
// no LDS, scalar stores) + CLOSED-FORM predict phase:
//   P(h) = F^h Pf F^h' + sum_{i<h} F^i Q F^i'  ->  P00/P02/P22 are cubics in h
// so each output step is 3 Horner cubics + 2 fma for mu, all iterations
// independent (no loop-carried P recursion).
__global__ __launch_bounds__(TPB) void kalman_v6(
    const float* __restrict__ hist,
    const float* __restrict__ vsx_p, const float* __restrict__ vsy_p,
    const float* __restrict__ asx_p, const float* __restrict__ asy_p,
    const float* __restrict__ GR_p,  const float* __restrict__ coefG_p,
    float* __restrict__ out, int B, int len_pred)
{
    const int b = blockIdx.x * TPB + threadIdx.x;
    if (b >= B) return;

    // ---- measurements first: 16 coalesced float2 loads, all in flight ----
    float2 z[LEN_HIST];
    #pragma unroll
    for (int t = 0; t < LEN_HIST; ++t)
        z[t] = *reinterpret_cast<const float2*>(hist + ((size_t)t * B + b) * 2);

    // ---- constants: Q (triangle), R ----
    const float d = DT;
    const float d2 = d * d;
    const float Gv0 = DT * DT * 0.5f, Gv1 = DT, Gv2 = DT * DT * 0.5f, Gv3 = DT;
    const float ax2 = asx_p[0] * asx_p[0];
    const float ay2 = asy_p[0] * asy_p[0];
    const float g0 = Gv0 * tanhf(coefG_p[0]);
    const float g1 = Gv1 * tanhf(coefG_p[1]);
    const float g2 = Gv2 * tanhf(coefG_p[2]);
    const float g3 = Gv3 * tanhf(coefG_p[3]);
    const float Q00 = g0 * g0 * ax2, Q01 = g0 * g1 * ax2;
    const float Q02 = g0 * g2,       Q03 = g0 * g3;
    const float Q11 = g1 * g1 * ax2, Q12 = g1 * g2, Q13 = g1 * g3;
    const float Q22 = g2 * g2 * ay2, Q23 = g2 * g3 * ay2, Q33 = g3 * g3 * ay2;
    const float GR0 = GR_p[0], GR1 = GR_p[1];
    const float R00 = GR0 * GR0, R01 = GR0 * GR1, R11 = GR1 * GR1;

    // ---- init ----
    float X0 = z[0].x, X1 = (z[1].x - z[0].x) / DT;
    float X2 = z[0].y, X3 = (z[1].y - z[0].y) / DT;
    float P00 = R00,                 P01 = 0.f, P02 = 0.f, P03 = 0.f;
    float P11 = vsx_p[0] * vsx_p[0], P12 = 0.f, P13 = 0.f;
    float P22 = R11,                 P23 = 0.f;
    float P33 = vsy_p[0] * vsy_p[0];

    // ---- filter: 15 updates, symmetric triangle, simple-form (v4) ----
    #pragma unroll
    for (int t = 1; t < LEN_HIST; ++t) {
        const float n00 = P00 + d * (P01 + P01 + d * P11) + Q00;
        const float n01 = P01 + d * P11 + Q01;
        const float n02 = P02 + d * (P03 + P12 + d * P13) + Q02;
        const float n03 = P03 + d * P13 + Q03;
        const float n11 = P11 + Q11;
        const float n12 = P12 + d * P13 + Q12;
        const float n13 = P13 + Q13;
        const float n22 = P22 + d * (P23 + P23 + d * P33) + Q22;
        const float n23 = P23 + d * P33 + Q23;
        const float n33 = P33 + Q33;

        X0 += d * X1; X2 += d * X3;
        const float y0 = z[t].x - X0;
        const float y1 = z[t].y - X2;

        const float S00 = n00 + R00, S01 = n02 + R01, S11 = n22 + R11;
        const float inv = 1.0f / (S00 * S11 - S01 * S01);
        const float Si00 = S11 * inv, Si01 = -S01 * inv, Si11 = S00 * inv;

        const float K00 = n00 * Si00 + n02 * Si01, K01 = n00 * Si01 + n02 * Si11;
        const float K10 = n01 * Si00 + n12 * Si01, K11 = n01 * Si01 + n12 * Si11;
        const float K20 = n02 * Si00 + n22 * Si01, K21 = n02 * Si01 + n22 * Si11;
        const float K30 = n03 * Si00 + n23 * Si01, K31 = n03 * Si01 + n23 * Si11;

        X0 += K00 * y0 + K01 * y1;
        X1 += K10 * y0 + K11 * y1;
        X2 += K20 * y0 + K21 * y1;
        X3 += K30 * y0 + K31 * y1;

        P00 = n00 - K00 * n00 - K01 * n02;
        P01 = n01 - K00 * n01 - K01 * n12;
        P02 = n02 - K00 * n02 - K01 * n22;
        P03 = n03 - K00 * n03 - K01 * n23;
        P11 = n11 - K10 * n01 - K11 * n12;
        P12 = n12 - K10 * n02 - K11 * n22;
        P13 = n13 - K10 * n03 - K11 * n23;
        P22 = n22 - K20 * n02 - K21 * n22;
        P23 = n23 - K20 * n03 - K21 * n23;
        P33 = n33 - K30 * n03 - K31 * n23;
    }

    // ---- closed-form cubic coefficients for P00(h), P02(h), P22(h) ----
    // P00(h) = c0 + c1 h + c2 h^2 + c3 h^3   (verified vs recursion at h=1,2)
    const float c0 = P00;
    const float c1 = 2.f * d * P01 + Q00 - d * Q01 + d2 * Q11 * (1.f / 6.f);
    const float c2 = d2 * P11 + d * Q01 - 0.5f * d2 * Q11;
    const float c3 = d2 * Q11 * (1.f / 3.f);

    const float f0 = P22;
    const float f1 = 2.f * d * P23 + Q22 - d * Q23 + d2 * Q33 * (1.f / 6.f);
    const float f2 = d2 * P33 + d * Q23 - 0.5f * d2 * Q33;
    const float f3 = d2 * Q33 * (1.f / 3.f);

    const float qs = Q03 + Q12;
    const float e0 = P02;
    const float e1 = d * (P03 + P12) + Q02 - 0.5f * d * qs + d2 * Q13 * (1.f / 6.f);
    const float e2 = d2 * P13 + 0.5f * d * qs - 0.5f * d2 * Q13;
    const float e3 = d2 * Q13 * (1.f / 3.f);

    const float dX1 = d * X1, dX3 = d * X3;

    // ---- prediction: independent per-l evaluation, scalar stores (v4) ----
    float* o = out + (size_t)b * 5;
    const size_t ostride = (size_t)B * 5;
    float hf = 1.0f;
    for (int l = 0; l < len_pred; ++l) {
        const float p00 = fmaf(hf, fmaf(hf, fmaf(hf, c3, c2), c1), c0);
        const float p22 = fmaf(hf, fmaf(hf, fmaf(hf, f3, f2), f1), f0);
        const float p02 = fmaf(hf, fmaf(hf, fmaf(hf, e3, e2), e1), e0);

        const float sx = sqrtf(p00);
        const float sy = sqrtf(p22);
        const float rho = p02 / (sx * sy);
        const float mux = fmaf(hf, dX1, X0);
        const float muy = fmaf(hf, dX3, X2);

        o[0] = mux; o[1] = muy; o[2] = sx; o[3] = sy; o[4] = rho;
        o += ostride;
        hf += 1.0f;
    }
}

extern "C" void kernel_launch(void* const* d_in, const int* in_sizes, int n_in,
                              void* d_out, int out_size, void* d_ws, size_t ws_size,
                              hipStream_t stream) {
    const float* hist  = (const float*)d_in[0];
    const float* vsx   = (const float*)d_in[1];
    const float* vsy   = (const float*)d_in[2];
    const float* asx   = (const float*)d_in[3];
    const float* asy   = (const float*)d_in[4];
    const float* GR    = (const float*)d_in[5];
    const float* coefG = (const float*)d_in[6];
    float* out = (float*)d_out;

    int B = in_sizes[0] / (LEN_HIST * 2);
    int len_pred = out_size / (B * 5);

    int grid = (B + TPB - 1) / TPB;
    kalman_v6<<<grid, TPB, 0, stream>>>(hist, vsx, vsy, asx, asy, GR, coefG,
                                        out, B, len_pred);
}